// Round 1
// baseline (2128.890 us; speedup 1.0000x reference)
//
#include <hip/hip_runtime.h>
#include <hip/hip_fp16.h>
#include <math.h>

// Problem constants (B=4, S=2048, DIN=4096, DOUT=16384)
#define M_DIM 8192   // B*S
#define N_DIM 16384  // DOUT
#define K_DIM 4096   // DIN

typedef _Float16 half8 __attribute__((ext_vector_type(8)));
typedef _Float16 half4v __attribute__((ext_vector_type(4)));
typedef float f32x4 __attribute__((ext_vector_type(4)));
typedef int i32x4 __attribute__((ext_vector_type(4)));

// async global->LDS, 16B per lane; LDS dest = wave-uniform base + lane*16
#define GLOAD_LDS16(gp, lp)                                                     \
  __builtin_amdgcn_global_load_lds(                                             \
      (const __attribute__((address_space(1))) unsigned int*)(gp),              \
      (__attribute__((address_space(3))) unsigned int*)(lp), 16, 0, 0)

__device__ __forceinline__ float gelu_tanh(float y) {
  float t = tanhf(0.7978845608028654f * (y + 0.044715f * y * y * y));
  return 0.5f * y * (1.0f + t);
}

// ---------- conversion pre-passes ----------
__global__ void cvt_f32_to_f16_k(const float* __restrict__ in,
                                 _Float16* __restrict__ out, int n8) {
  int i = blockIdx.x * blockDim.x + threadIdx.x;
  if (i >= n8) return;
  f32x4 a = ((const f32x4*)in)[2 * (size_t)i];
  f32x4 b = ((const f32x4*)in)[2 * (size_t)i + 1];
  half8 h;
  h[0] = (_Float16)a[0]; h[1] = (_Float16)a[1];
  h[2] = (_Float16)a[2]; h[3] = (_Float16)a[3];
  h[4] = (_Float16)b[0]; h[5] = (_Float16)b[1];
  h[6] = (_Float16)b[2]; h[7] = (_Float16)b[3];
  ((half8*)out)[i] = h;
}

__global__ void cvt_i32_to_f16_k(const int* __restrict__ in,
                                 _Float16* __restrict__ out, int n8) {
  int i = blockIdx.x * blockDim.x + threadIdx.x;
  if (i >= n8) return;
  i32x4 a = ((const i32x4*)in)[2 * (size_t)i];
  i32x4 b = ((const i32x4*)in)[2 * (size_t)i + 1];
  half8 h;
  h[0] = (_Float16)(float)a[0]; h[1] = (_Float16)(float)a[1];
  h[2] = (_Float16)(float)a[2]; h[3] = (_Float16)(float)a[3];
  h[4] = (_Float16)(float)b[0]; h[5] = (_Float16)(float)b[1];
  h[6] = (_Float16)(float)b[2]; h[7] = (_Float16)(float)b[3];
  ((half8*)out)[i] = h;
}

// ---------- GEMM: C = A[M,K] * W[N,K]^T, fused dequant+bias+GELU ----------
// 128x128 block tile, BK=32, 256 threads (4 waves, 2x2), 16x16x32 f16 MFMA.
// CONV=false: A/W already f16 in workspace, staged via global_load_lds x16.
// CONV=true : convert fp32/int32 -> f16 inline during staging (ws fallback).
template <bool CONV>
__global__ void q8gemm_gelu(const _Float16* __restrict__ Ah,
                            const _Float16* __restrict__ Wh,
                            const float* __restrict__ Af,
                            const int* __restrict__ Wi,
                            const float* __restrict__ w_scale,
                            const float* __restrict__ bias,
                            float* __restrict__ out) {
  __shared__ _Float16 sA[128 * 32];  // 8 KB, row-major [row][k], NO padding
  __shared__ _Float16 sB[128 * 32];  // (global_load_lds requires exact order)

  const int tid = threadIdx.x;
  const int lane = tid & 63;
  const int wave = tid >> 6;
  const int ln15 = lane & 15;
  const int quad = lane >> 4;
  const int waveM = wave >> 1;
  const int waveN = wave & 1;

  // group-of-8-M block swizzle for L2 reuse (64 m-tiles, 128 n-tiles)
  int bid = blockIdx.x;
  int group_id = bid >> 10;           // 8 * 128 = 1024 blocks per group
  int within = bid & 1023;
  int pid_m = group_id * 8 + (within & 7);
  int pid_n = within >> 3;

  const int rowA0 = pid_m * 128;
  const int rowB0 = pid_n * 128;

  f32x4 acc[4][4] = {};

  // LDS fragment read offsets (f16 elements): A[m=ln15][k=quad*8+j]
  int aOff[4], bOff[4];
#pragma unroll
  for (int i = 0; i < 4; i++) {
    aOff[i] = (waveM * 64 + i * 16 + ln15) * 32 + quad * 8;
    bOff[i] = (waveN * 64 + i * 16 + ln15) * 32 + quad * 8;
  }

  // staging chunk indices (16B chunks: tile = 128 rows x 64 B = 512 chunks)
  const int c0 = wave * 64 + lane;
  const int c1 = c0 + 256;

  for (int k0 = 0; k0 < K_DIM; k0 += 32) {
    if constexpr (!CONV) {
      const _Float16* ga0 =
          Ah + (size_t)(rowA0 + (c0 >> 2)) * K_DIM + k0 + ((c0 & 3) << 3);
      const _Float16* ga1 =
          Ah + (size_t)(rowA0 + (c1 >> 2)) * K_DIM + k0 + ((c1 & 3) << 3);
      const _Float16* gb0 =
          Wh + (size_t)(rowB0 + (c0 >> 2)) * K_DIM + k0 + ((c0 & 3) << 3);
      const _Float16* gb1 =
          Wh + (size_t)(rowB0 + (c1 >> 2)) * K_DIM + k0 + ((c1 & 3) << 3);
      GLOAD_LDS16(ga0, &sA[(wave * 64) * 8]);
      GLOAD_LDS16(ga1, &sA[(wave * 64 + 256) * 8]);
      GLOAD_LDS16(gb0, &sB[(wave * 64) * 8]);
      GLOAD_LDS16(gb1, &sB[(wave * 64 + 256) * 8]);
    } else {
#pragma unroll
      for (int i = 0; i < 4; i++) {
        int c = tid + i * 256;  // 4-element chunks, 1024 total
        int r = c >> 3;
        int col = (c & 7) << 2;
        f32x4 av = *(const f32x4*)(Af + (size_t)(rowA0 + r) * K_DIM + k0 + col);
        half4v ah;
        ah[0] = (_Float16)av[0]; ah[1] = (_Float16)av[1];
        ah[2] = (_Float16)av[2]; ah[3] = (_Float16)av[3];
        *(half4v*)&sA[r * 32 + col] = ah;
        i32x4 wv = *(const i32x4*)(Wi + (size_t)(rowB0 + r) * K_DIM + k0 + col);
        half4v wh;
        wh[0] = (_Float16)(float)wv[0]; wh[1] = (_Float16)(float)wv[1];
        wh[2] = (_Float16)(float)wv[2]; wh[3] = (_Float16)(float)wv[3];
        *(half4v*)&sB[r * 32 + col] = wh;
      }
    }
    __syncthreads();  // drains vmcnt (global_load_lds) + lgkm

    half8 aF[4], bF[4];
#pragma unroll
    for (int i = 0; i < 4; i++) {
      aF[i] = *(const half8*)&sA[aOff[i]];
      bF[i] = *(const half8*)&sB[bOff[i]];
    }
#pragma unroll
    for (int mi = 0; mi < 4; mi++)
#pragma unroll
      for (int ni = 0; ni < 4; ni++)
        acc[mi][ni] = __builtin_amdgcn_mfma_f32_16x16x32_f16(
            aF[mi], bF[ni], acc[mi][ni], 0, 0, 0);

    __syncthreads();  // protect LDS before next stage overwrites
  }

  // epilogue: dequant * scale + bias, tanh-GELU, store fp32
  // C/D layout: col = ln15, row = quad*4 + r
#pragma unroll
  for (int ni = 0; ni < 4; ni++) {
    int n_g = rowB0 + waveN * 64 + ni * 16 + ln15;
    float sc = w_scale[n_g];
    float bi = bias[n_g];
#pragma unroll
    for (int mi = 0; mi < 4; mi++) {
      int r0 = rowA0 + waveM * 64 + mi * 16 + quad * 4;
#pragma unroll
      for (int r = 0; r < 4; r++) {
        float y = acc[mi][ni][r] * sc + bi;
        out[(size_t)(r0 + r) * N_DIM + n_g] = gelu_tanh(y);
      }
    }
  }
}

extern "C" void kernel_launch(void* const* d_in, const int* in_sizes, int n_in,
                              void* d_out, int out_size, void* d_ws,
                              size_t ws_size, hipStream_t stream) {
  const float* hs = (const float*)d_in[0];   // [M,K] fp32
  const int* w8 = (const int*)d_in[1];       // [N,K] int32 (int8-valued)
  const float* wsc = (const float*)d_in[2];  // [N]
  const float* bs = (const float*)d_in[3];   // [N]
  float* out = (float*)d_out;                // [M,N] fp32

  const size_t needA = (size_t)M_DIM * K_DIM * sizeof(_Float16);  // 64 MiB
  const size_t needW = (size_t)N_DIM * K_DIM * sizeof(_Float16);  // 128 MiB
  const int nblocks = (M_DIM / 128) * (N_DIM / 128);              // 8192

  if (ws_size >= needA + needW) {
    _Float16* Ah = (_Float16*)d_ws;
    _Float16* Wh = (_Float16*)((char*)d_ws + needA);
    int n8a = M_DIM * K_DIM / 8;
    int n8w = N_DIM * K_DIM / 8;
    cvt_f32_to_f16_k<<<n8a / 256, 256, 0, stream>>>(hs, Ah, n8a);
    cvt_i32_to_f16_k<<<n8w / 256, 256, 0, stream>>>(w8, Wh, n8w);
    q8gemm_gelu<false><<<nblocks, 256, 0, stream>>>(Ah, Wh, nullptr, nullptr,
                                                    wsc, bs, out);
  } else {
    q8gemm_gelu<true><<<nblocks, 256, 0, stream>>>(nullptr, nullptr, hs, w8,
                                                   wsc, bs, out);
  }
}